// Round 8
// baseline (184.943 us; speedup 1.0000x reference)
//
#include <hip/hip_runtime.h>

// CRF log-partition, MI355X — R8: 4-segment split with MFMA transfer matrices.
// R2 (validated, 68us) showed the vector step is ~648cyc of mostly-irreducible
// latency; R3-R6 all failed to beat it. This version cuts the CHAIN: Z =
// alpha_a^T * M1 * M2 * x_c with a=T/4, b=T/2, c=3T/4 (T=len-1):
//   fwd  (bid 0-63):   alpha_a via R2's validated vector recurrence
//   bwd  (bid 64-127): x_c     via R2's validated backward recurrence
//   mat1 (bid 128-191): M1^T = Prod_{t=a+1..b} (D_{s_t} E^T)  [left-mult]
//   mat2 (bid 192-255): M2^T over t=b+1..c
// Matrix segments: track M^T so COLUMN-strips evolve independently under
// left-mult -> wave r owns M^T[:,32r..32r+32), NO barriers. Per step:
//   D = E^T * B  (32x v_mfma_f32_32x32x16_f16; A=E^T frags constant ->
//   AGPR-parkable, MFMA reads AGPR natively), then row-scale by s_t[row]
//   and 2^-eS (renorm) during the intra-lane D->B f16 repack.
// Layout facts used: C/D col=lane&31, row=(reg&3)+8*(reg>>2)+4*(lane>>5)
// [HW-verified]. A/B k-map assumed k=4h+(e&3)+8*(e>>2) (h=lane>>5) — the
// matmul is invariant to any common K-permutation, so only A/B symmetry
// matters, not the actual map. Renorm: f32 exponent of a reference D entry,
// exact pow2 scaling, per-strip o accumulator (combine folds strip scales).
// crf_combine: stage alpha (strip-scaled) -> v1 = a^T M1 -> v2 = v1 M2 ->
// dot with x_c -> LN2*(sum_o + log2).

#define LOG2E 1.4426950408889634f
#define LN2   0.6931471805599453f

#define LDS_BARRIER() asm volatile("s_waitcnt lgkmcnt(0)\n\ts_barrier" ::: "memory")
#define LGKM0() asm volatile("s_waitcnt lgkmcnt(0)" ::: "memory")

typedef float    f2  __attribute__((ext_vector_type(2)));
typedef float    f4  __attribute__((ext_vector_type(4)));
typedef float    f16f __attribute__((ext_vector_type(16)));
typedef unsigned u4  __attribute__((ext_vector_type(4)));
typedef _Float16 h2  __attribute__((ext_vector_type(2)));
typedef _Float16 h8  __attribute__((ext_vector_type(8)));

#define PKRTZ(a, b) __builtin_bit_cast(h2, __builtin_amdgcn_cvt_pkrtz((a), (b)))
#define BITS(x)     __builtin_bit_cast(unsigned, (x))

template <int CTRL>
__device__ __forceinline__ float dpp_f(float x) {
    return __int_as_float(
        __builtin_amdgcn_mov_dpp(__float_as_int(x), CTRL, 0xF, 0xF, false));
}

__global__ __launch_bounds__(256)
__attribute__((amdgpu_waves_per_eu(1, 1)))
void crf_fused(
    const float* __restrict__ emissions,   // [64, 512, 128]
    const float* __restrict__ transitions, // [128, 128]
    const float* __restrict__ start_t,     // [128]
    const float* __restrict__ end_t,       // [128]
    const int*   __restrict__ lengths,     // [64]
    float* __restrict__ wsV,               // [2][64][128]
    int*   __restrict__ wsO,               // [2][64]
    int*   __restrict__ wsMo,              // [2][64][4]
    _Float16* __restrict__ wsMh)           // [2][64][128][128]
{
    constexpr int N = 128;
    constexpr int L = 512;
    const int bid  = blockIdx.x;
    const int role = bid >> 6;   // 0 fwd, 1 bwd, 2 mat1, 3 mat2
    const int b    = bid & 63;
    const int tid  = threadIdx.x;

    const int len = lengths[b];
    const int T   = len - 1;
    const int qa  = T >> 2;
    const int qb  = T >> 1;
    const int qc  = (3 * T) >> 2;
    const float* eb = emissions + (size_t)b * L * N;

    __shared__ alignas(16) float pbuf[2][80];     // vector roles
    __shared__ alignas(16) float sbuf[4][128];    // matrix roles (per wave)

    if (role < 2) {
        // ================= VECTOR ROLES (R2 code, re-parameterized) =========
        const bool isf = (role == 0);
        const int  g   = tid >> 2;
        const int  k   = tid & 3;

        h2 EA_0,  EA_1,  EA_2,  EA_3,  EA_4,  EA_5,  EA_6,  EA_7;
        h2 EA_8,  EA_9,  EA_10, EA_11, EA_12, EA_13, EA_14, EA_15;
        h2 EB_0,  EB_1,  EB_2,  EB_3,  EB_4,  EB_5,  EB_6,  EB_7;
        h2 EB_8,  EB_9,  EB_10, EB_11, EB_12, EB_13, EB_14, EB_15;
        if (isf) {
            const float* tb = transitions + (size_t)(32 * k) * N + 2 * g;
#define INIT_F(m)                                                              \
            {                                                                  \
                f2 r0 = *reinterpret_cast<const f2*>(tb + (size_t)(2 * (m)) * N); \
                f2 r1 = *reinterpret_cast<const f2*>(tb + (size_t)(2 * (m) + 1) * N); \
                EA_##m = PKRTZ(__builtin_amdgcn_exp2f(r0.x * LOG2E),           \
                               __builtin_amdgcn_exp2f(r1.x * LOG2E));          \
                EB_##m = PKRTZ(__builtin_amdgcn_exp2f(r0.y * LOG2E),           \
                               __builtin_amdgcn_exp2f(r1.y * LOG2E));          \
            }
            INIT_F(0)  INIT_F(1)  INIT_F(2)  INIT_F(3)
            INIT_F(4)  INIT_F(5)  INIT_F(6)  INIT_F(7)
            INIT_F(8)  INIT_F(9)  INIT_F(10) INIT_F(11)
            INIT_F(12) INIT_F(13) INIT_F(14) INIT_F(15)
#undef INIT_F
        } else {
            const float* ra_ = transitions + (size_t)(2 * g) * N + 32 * k;
            const float* rb_ = transitions + (size_t)(2 * g + 1) * N + 32 * k;
#define INIT_B(m)                                                              \
            {                                                                  \
                f2 r0 = *reinterpret_cast<const f2*>(ra_ + 2 * (m));           \
                f2 r1 = *reinterpret_cast<const f2*>(rb_ + 2 * (m));           \
                EA_##m = PKRTZ(__builtin_amdgcn_exp2f(r0.x * LOG2E),           \
                               __builtin_amdgcn_exp2f(r0.y * LOG2E));          \
                EB_##m = PKRTZ(__builtin_amdgcn_exp2f(r1.x * LOG2E),           \
                               __builtin_amdgcn_exp2f(r1.y * LOG2E));          \
            }
            INIT_B(0)  INIT_B(1)  INIT_B(2)  INIT_B(3)
            INIT_B(4)  INIT_B(5)  INIT_B(6)  INIT_B(7)
            INIT_B(8)  INIT_B(9)  INIT_B(10) INIT_B(11)
            INIT_B(12) INIT_B(13) INIT_B(14) INIT_B(15)
#undef INIT_B
        }

        int n_steps, e0, dstep; bool zfinal;
        if (isf) {
            n_steps = qa; e0 = 1; dstep = 1; zfinal = false;
        } else {
            int total = T - qc;
            n_steps = total > 0 ? total - 1 : 0;
            e0 = len - 2; if (e0 < 0) e0 = 0;
            dstep = -1;
            zfinal = total > 0;
        }

        int o = 0, cur = 0;
        float qA, qB;
        {
            const float* base = isf ? start_t : end_t;
            f2 bt = *reinterpret_cast<const f2*>(base + 2 * g);
            f2 ev;
            if (isf)         ev = *reinterpret_cast<const f2*>(eb + 2 * g);
            else if (zfinal) ev = *reinterpret_cast<const f2*>(eb + (size_t)(len - 1) * N + 2 * g);
            else           { ev.x = 0.f; ev.y = 0.f; }
            qA = __builtin_amdgcn_exp2f((bt.x + ev.x) * LOG2E);
            qB = __builtin_amdgcn_exp2f((bt.y + ev.y) * LOG2E);
            if (k == 0)
                pbuf[0][(g >> 4) * 20 + (g & 15)] =
                    __builtin_bit_cast(float, PKRTZ(qA, qB));
        }
        LDS_BARRIER();

        auto eidx = [&](int n) {
            int nn = (n < n_steps) ? n : (n_steps - 1);
            if (nn < 0) nn = 0;
            return e0 + dstep * nn;
        };
        auto ldE = [&](int tt) {
            return *reinterpret_cast<const f2*>(eb + (size_t)tt * N + 2 * g);
        };

        auto STEP = [&](f2 ecur) {
            float q0w = pbuf[cur][0];
            const float4* pv = reinterpret_cast<const float4*>(&pbuf[cur][k * 20]);
            float4 Qa = pv[0], Qb = pv[1], Qc = pv[2], Qd = pv[3];

            unsigned u0 = __float_as_uint(q0w);
            int eS = (int)((u0 >> 10) & 0x1Fu) - 15;
            o += eS;
            float feS = (float)eS;
            float esA = __builtin_amdgcn_exp2f(ecur.x * LOG2E - feS);
            float esB = __builtin_amdgcn_exp2f(ecur.y * LOG2E - feS);

            float aA0 = 0.f, aA1 = 0.f, aB0 = 0.f, aB1 = 0.f;
#define D0(m_, Qc_)                                                            \
            {                                                                  \
                h2 pm = __builtin_bit_cast(h2, Qc_);                           \
                aA0 = __builtin_amdgcn_fdot2(pm, EA_##m_, aA0, false);         \
                aB0 = __builtin_amdgcn_fdot2(pm, EB_##m_, aB0, false);         \
            }
#define D1(m_, Qc_)                                                            \
            {                                                                  \
                h2 pm = __builtin_bit_cast(h2, Qc_);                           \
                aA1 = __builtin_amdgcn_fdot2(pm, EA_##m_, aA1, false);         \
                aB1 = __builtin_amdgcn_fdot2(pm, EB_##m_, aB1, false);         \
            }
            D0(0,  Qa.x) D1(1,  Qa.y) D0(2,  Qa.z) D1(3,  Qa.w)
            D0(4,  Qb.x) D1(5,  Qb.y) D0(6,  Qb.z) D1(7,  Qb.w)
            D0(8,  Qc.x) D1(9,  Qc.y) D0(10, Qc.z) D1(11, Qc.w)
            D0(12, Qd.x) D1(13, Qd.y) D0(14, Qd.z) D1(15, Qd.w)
#undef D0
#undef D1
            float dA = aA0 + aA1;
            float dB = aB0 + aB1;
            dA += dpp_f<0xB1>(dA); dB += dpp_f<0xB1>(dB);
            dA += dpp_f<0x4E>(dA); dB += dpp_f<0x4E>(dB);

            qA = esA * dA;
            qB = esB * dB;
            cur ^= 1;
            if (k == 0)
                pbuf[cur][(g >> 4) * 20 + (g & 15)] =
                    __builtin_bit_cast(float, PKRTZ(qA, qB));
            LDS_BARRIER();
        };

        f2 ra = ldE(eidx(0));
        f2 rb = ldE(eidx(1));
        f2 rc = ldE(eidx(2));
        f2 rd = ldE(eidx(3));

        int n = 0;
        while (n < n_steps) {
            STEP(ra); ra = ldE(eidx(n + 4)); ++n; if (n >= n_steps) break;
            STEP(rb); rb = ldE(eidx(n + 4)); ++n; if (n >= n_steps) break;
            STEP(rc); rc = ldE(eidx(n + 4)); ++n; if (n >= n_steps) break;
            STEP(rd); rd = ldE(eidx(n + 4)); ++n;
        }
        if (zfinal) { f2 z; z.x = 0.f; z.y = 0.f; STEP(z); }

        float* wv = wsV + (size_t)(role * 64 + b) * 128;
        if (k == 0) {
            f2 q; q.x = qA; q.y = qB;
            *reinterpret_cast<f2*>(wv + 2 * g) = q;
        }
        if (tid == 0) wsO[role * 64 + b] = o;

    } else {
        // ================= MATRIX ROLES =====================================
        const int w    = tid >> 6;        // wave = strip (M^T cols [32w..))
        const int lidx = tid & 63;
        const int h    = (tid >> 5) & 1;  // lane>>5
        const int nn   = tid & 31;        // n = lane&31
        const int matid = role - 2;
        const int tlo   = matid ? qb : qa;
        const int nm    = matid ? (qc - qb) : (qb - qa);

        // ---- A = E^T fragments: Afr[mt][kb], A[m][k] = exp(T[k][32mt+m])
        // k-map: k = 16kb + 4h + (e&3) + 8*(e>>2); e -> (reg e>>1, half e&1)
        h8 Afr[4][8];
        #pragma unroll
        for (int mt = 0; mt < 4; ++mt) {
            #pragma unroll
            for (int kb = 0; kb < 8; ++kb) {
                u4 au;
                #pragma unroll
                for (int ep = 0; ep < 4; ++ep) {
                    int ee0 = 2 * ep, ee1 = 2 * ep + 1;
                    int k0 = 16 * kb + 4 * h + (ee0 & 3) + 8 * (ee0 >> 2);
                    int k1 = 16 * kb + 4 * h + (ee1 & 3) + 8 * (ee1 >> 2);
                    float v0 = __builtin_amdgcn_exp2f(
                        transitions[k0 * N + 32 * mt + nn] * LOG2E);
                    float v1 = __builtin_amdgcn_exp2f(
                        transitions[k1 * N + 32 * mt + nn] * LOG2E);
                    au[ep] = BITS(PKRTZ(v0, v1));
                }
                Afr[mt][kb] = __builtin_bit_cast(h8, au);
            }
        }

        // ---- B init = identity strip: 1.0 where k_global == 32w + n
        h8 B0[8], B1[8];
        const int colg = 32 * w + nn;
        #pragma unroll
        for (int kb = 0; kb < 8; ++kb) {
            u4 bu; bu[0] = 0u; bu[1] = 0u; bu[2] = 0u; bu[3] = 0u;
            #pragma unroll
            for (int e = 0; e < 8; ++e) {
                int kk = 16 * kb + 4 * h + (e & 3) + 8 * (e >> 2);
                if (kk == colg)
                    bu[e >> 1] |= 0x3C00u << (16 * (e & 1));
            }
            B0[kb] = __builtin_bit_cast(h8, bu);
        }
        int o = 0;

        auto ldEm = [&](int q) {
            int qq = q; if (qq > nm - 1) qq = nm - 1; if (qq < 0) qq = 0;
            int t = tlo + 1 + qq;
            return *reinterpret_cast<const f2*>(eb + (size_t)t * N + 2 * lidx);
        };

        auto STEPm = [&](h8 (&Bs)[8], h8 (&Bd)[8], f2 ev) {
            // per-wave s-buffer: s[row] = exp(e_t[row]); lane fills its pair
            f2 sp;
            sp.x = __builtin_amdgcn_exp2f(ev.x * LOG2E);
            sp.y = __builtin_amdgcn_exp2f(ev.y * LOG2E);
            *reinterpret_cast<f2*>(&sbuf[w][2 * lidx]) = sp;
            LGKM0();   // same-wave cross-lane RAW (R4-validated pattern)

            float sc = 1.0f;
            #pragma unroll
            for (int mt = 0; mt < 4; ++mt) {
                f4 s0 = *reinterpret_cast<const f4*>(&sbuf[w][32 * mt + 4 * h]);
                f4 s1 = *reinterpret_cast<const f4*>(&sbuf[w][32 * mt + 8 + 4 * h]);
                f4 s2 = *reinterpret_cast<const f4*>(&sbuf[w][32 * mt + 16 + 4 * h]);
                f4 s3 = *reinterpret_cast<const f4*>(&sbuf[w][32 * mt + 24 + 4 * h]);
                f16f D = {0.f,0.f,0.f,0.f,0.f,0.f,0.f,0.f,
                          0.f,0.f,0.f,0.f,0.f,0.f,0.f,0.f};
                #pragma unroll
                for (int kb = 0; kb < 8; ++kb)
                    D = __builtin_amdgcn_mfma_f32_32x32x16_f16(
                        Afr[mt][kb], Bs[kb], D, 0, 0, 0);
                if (mt == 0) {
                    int rb_ = __builtin_amdgcn_readfirstlane(__float_as_int(D[0]));
                    int ex = (int)(((unsigned)rb_ >> 23) & 255u) - 127;
                    if (ex > 24) ex = 24; if (ex < -24) ex = -24;
                    o += ex;
                    sc = __int_as_float((unsigned)(127 - ex) << 23);
                }
                u4 lo, hi;
                lo[0] = BITS(PKRTZ(D[0]  * s0.x * sc, D[1]  * s0.y * sc));
                lo[1] = BITS(PKRTZ(D[2]  * s0.z * sc, D[3]  * s0.w * sc));
                lo[2] = BITS(PKRTZ(D[4]  * s1.x * sc, D[5]  * s1.y * sc));
                lo[3] = BITS(PKRTZ(D[6]  * s1.z * sc, D[7]  * s1.w * sc));
                hi[0] = BITS(PKRTZ(D[8]  * s2.x * sc, D[9]  * s2.y * sc));
                hi[1] = BITS(PKRTZ(D[10] * s2.z * sc, D[11] * s2.w * sc));
                hi[2] = BITS(PKRTZ(D[12] * s3.x * sc, D[13] * s3.y * sc));
                hi[3] = BITS(PKRTZ(D[14] * s3.z * sc, D[15] * s3.w * sc));
                Bd[2 * mt]     = __builtin_bit_cast(h8, lo);
                Bd[2 * mt + 1] = __builtin_bit_cast(h8, hi);
            }
        };

        f2 ra = ldEm(0), rb = ldEm(1);
        int q = 0;
        while (q + 1 < nm) {
            STEPm(B0, B1, ra); ra = ldEm(q + 2);
            STEPm(B1, B0, rb); rb = ldEm(q + 3);
            q += 2;
        }
        if (q < nm) {
            STEPm(B0, B1, ra);
            #pragma unroll
            for (int kb = 0; kb < 8; ++kb) B0[kb] = B1[kb];
        }

        // ---- store M (f16): M[i][j] = M^T[j][i], i = 32w+n fixed per lane
        _Float16* wm = wsMh + ((size_t)(matid * 64 + b) * 128 + (32 * w + nn)) * 128;
        #pragma unroll
        for (int kb = 0; kb < 8; ++kb) {
            u4 bu = __builtin_bit_cast(u4, B0[kb]);
            #pragma unroll
            for (int e = 0; e < 8; ++e) {
                int j = 16 * kb + 4 * h + (e & 3) + 8 * (e >> 2);
                unsigned dw = bu[e >> 1];
                unsigned short us = (unsigned short)((e & 1) ? (dw >> 16)
                                                             : (dw & 0xFFFFu));
                wm[j] = __builtin_bit_cast(_Float16, us);
            }
        }
        if (lidx == 0) wsMo[(matid * 64 + b) * 4 + w] = o;
    }
}

__global__ __launch_bounds__(128)
void crf_combine(const float* __restrict__ wsV, const int* __restrict__ wsO,
                 const int* __restrict__ wsMo, const _Float16* __restrict__ wsMh,
                 float* __restrict__ out)
{
    const int b = blockIdx.x;
    const int j = threadIdx.x;   // 0..127
    __shared__ float stage[128];
    __shared__ float redw[2];

    int o10 = wsMo[(0 * 64 + b) * 4 + 0], o11 = wsMo[(0 * 64 + b) * 4 + 1];
    int o12 = wsMo[(0 * 64 + b) * 4 + 2], o13 = wsMo[(0 * 64 + b) * 4 + 3];
    int o20 = wsMo[(1 * 64 + b) * 4 + 0], o21 = wsMo[(1 * 64 + b) * 4 + 1];
    int o22 = wsMo[(1 * 64 + b) * 4 + 2], o23 = wsMo[(1 * 64 + b) * 4 + 3];
    int O1 = max(max(o10, o11), max(o12, o13));
    int O2 = max(max(o20, o21), max(o22, o23));

    float al = wsV[(size_t)(0 * 64 + b) * 128 + j];
    int r1 = wsMo[(0 * 64 + b) * 4 + (j >> 5)];
    stage[j] = al * __builtin_amdgcn_exp2f((float)(r1 - O1));
    __syncthreads();

    float v1 = 0.f;
    const _Float16* M1 = wsMh + (size_t)(0 * 64 + b) * 128 * 128;
    #pragma unroll 8
    for (int i = 0; i < 128; ++i)
        v1 += stage[i] * (float)M1[(size_t)i * 128 + j];
    __syncthreads();

    int r2 = wsMo[(1 * 64 + b) * 4 + (j >> 5)];
    stage[j] = v1 * __builtin_amdgcn_exp2f((float)(r2 - O2));
    __syncthreads();

    float v2 = 0.f;
    const _Float16* M2 = wsMh + (size_t)(1 * 64 + b) * 128 * 128;
    #pragma unroll 8
    for (int i = 0; i < 128; ++i)
        v2 += stage[i] * (float)M2[(size_t)i * 128 + j];

    float term = v2 * wsV[(size_t)(1 * 64 + b) * 128 + j];
    #pragma unroll
    for (int s = 1; s < 64; s <<= 1) term += __shfl_xor(term, s);
    if ((j & 63) == 0) redw[j >> 6] = term;
    __syncthreads();
    if (j == 0) {
        float V = redw[0] + redw[1];
        out[b] = LN2 * ((float)(wsO[b] + wsO[64 + b] + O1 + O2) +
                        __builtin_amdgcn_logf(V));
    }
}

extern "C" void kernel_launch(void* const* d_in, const int* in_sizes, int n_in,
                              void* d_out, int out_size, void* d_ws, size_t ws_size,
                              hipStream_t stream) {
    const float* emissions   = (const float*)d_in[0];
    const float* transitions = (const float*)d_in[1];
    const float* start_t     = (const float*)d_in[2];
    const float* end_t       = (const float*)d_in[3];
    const int*   lengths     = (const int*)d_in[4];
    float* out = (float*)d_out;

    float*    wsV  = (float*)d_ws;                          // 65536 B
    int*      wsO  = (int*)((char*)d_ws + 65536);           // 512 B
    int*      wsMo = (int*)((char*)d_ws + 66048);           // 2048 B
    _Float16* wsMh = (_Float16*)((char*)d_ws + 68096);      // 4 MB

    crf_fused<<<dim3(256), dim3(256), 0, stream>>>(
        emissions, transitions, start_t, end_t, lengths, wsV, wsO, wsMo, wsMh);
    crf_combine<<<dim3(64), dim3(128), 0, stream>>>(wsV, wsO, wsMo, wsMh, out);
}

// Round 9
// 166.545 us; speedup vs baseline: 1.1105x; 1.1105x over previous
//
#include <hip/hip_runtime.h>

// CRF log-partition, MI355X — R9: R8's 4-segment MFMA algorithm, matrix step
// rebuilt on mfma_f32_16x16x32_f16. R8 validated (absmax 0.0) the transfer-
// matrix factorization Z = alpha_a^T M1 M2 x_c AND the self-consistent-kmap
// trick, but its 32x32x16 step was chain-bound: 4 chains x 8 dependent MFMAs
// (~128cyc each) ~= 1024 cyc + ~550 serial tail = 2190 cyc/step (MfmaUtil 10%).
// 16x16x32 gives 16 output tiles (128x32 strip), each K=128 in FOUR chained
// K=32 MFMAs -> 16 independent 4-deep chains: issue-bound ~294 cyc, latency
// hidden. Repack stays intra-lane with kmap mu(q,e)=4q+(e&3)+16(e>>2):
//   B[ks][ct] slot e  <-  D[rt=2ks+(e>>2)][ct] reg (e&3)   (same lane)
// (requires only sigma_A == sigma_B, the property R8 proved for the sibling
// shape). Row-scale via per-wave sbuf (8 b128 reads), renorm = f32 exponent
// of reference D element (readfirstlane), o += ex exact, clamp +-24.
// Segments rebalanced for step-cost ratio ~850/648: a = 0.29T, c = T-a,
// b = T/2; vector roles (fwd/bwd) are R2/R8's validated recurrence verbatim.
// Roles: bid>>6 = 0 fwd, 1 bwd, 2 mat1 (a,b], 3 mat2 (b,c]. crf_combine
// unchanged from R8 (validated).

#define LOG2E 1.4426950408889634f
#define LN2   0.6931471805599453f

#define LDS_BARRIER() asm volatile("s_waitcnt lgkmcnt(0)\n\ts_barrier" ::: "memory")
#define LGKM0() asm volatile("s_waitcnt lgkmcnt(0)" ::: "memory")

typedef float    f2  __attribute__((ext_vector_type(2)));
typedef float    f4  __attribute__((ext_vector_type(4)));
typedef unsigned u4  __attribute__((ext_vector_type(4)));
typedef _Float16 h2  __attribute__((ext_vector_type(2)));
typedef _Float16 h8  __attribute__((ext_vector_type(8)));

#define PKRTZ(a, b) __builtin_bit_cast(h2, __builtin_amdgcn_cvt_pkrtz((a), (b)))
#define BITS(x)     __builtin_bit_cast(unsigned, (x))

template <int CTRL>
__device__ __forceinline__ float dpp_f(float x) {
    return __int_as_float(
        __builtin_amdgcn_mov_dpp(__float_as_int(x), CTRL, 0xF, 0xF, false));
}

__global__ __launch_bounds__(256)
__attribute__((amdgpu_waves_per_eu(1, 1)))
void crf_fused(
    const float* __restrict__ emissions,   // [64, 512, 128]
    const float* __restrict__ transitions, // [128, 128]
    const float* __restrict__ start_t,     // [128]
    const float* __restrict__ end_t,       // [128]
    const int*   __restrict__ lengths,     // [64]
    float* __restrict__ wsV,               // [2][64][128]
    int*   __restrict__ wsO,               // [2][64]
    int*   __restrict__ wsMo,              // [2][64][4]
    _Float16* __restrict__ wsMh)           // [2][64][128][128]
{
    constexpr int N = 128;
    constexpr int L = 512;
    const int bid  = blockIdx.x;
    const int role = bid >> 6;   // 0 fwd, 1 bwd, 2 mat1, 3 mat2
    const int b    = bid & 63;
    const int tid  = threadIdx.x;

    const int len = lengths[b];
    const int T   = len - 1;
    const int qa  = (T * 29) / 100;          // vector/matrix balance point
    const int qb  = T >> 1;
    const int qc  = T - qa;
    const float* eb = emissions + (size_t)b * L * N;

    __shared__ alignas(16) float pbuf[2][80];     // vector roles
    __shared__ alignas(16) float sbuf[4][128];    // matrix roles (per wave)

    if (role < 2) {
        // ================= VECTOR ROLES (R2/R8 validated code) ==============
        const bool isf = (role == 0);
        const int  g   = tid >> 2;
        const int  k   = tid & 3;

        h2 EA_0,  EA_1,  EA_2,  EA_3,  EA_4,  EA_5,  EA_6,  EA_7;
        h2 EA_8,  EA_9,  EA_10, EA_11, EA_12, EA_13, EA_14, EA_15;
        h2 EB_0,  EB_1,  EB_2,  EB_3,  EB_4,  EB_5,  EB_6,  EB_7;
        h2 EB_8,  EB_9,  EB_10, EB_11, EB_12, EB_13, EB_14, EB_15;
        if (isf) {
            const float* tb = transitions + (size_t)(32 * k) * N + 2 * g;
#define INIT_F(m)                                                              \
            {                                                                  \
                f2 r0 = *reinterpret_cast<const f2*>(tb + (size_t)(2 * (m)) * N); \
                f2 r1 = *reinterpret_cast<const f2*>(tb + (size_t)(2 * (m) + 1) * N); \
                EA_##m = PKRTZ(__builtin_amdgcn_exp2f(r0.x * LOG2E),           \
                               __builtin_amdgcn_exp2f(r1.x * LOG2E));          \
                EB_##m = PKRTZ(__builtin_amdgcn_exp2f(r0.y * LOG2E),           \
                               __builtin_amdgcn_exp2f(r1.y * LOG2E));          \
            }
            INIT_F(0)  INIT_F(1)  INIT_F(2)  INIT_F(3)
            INIT_F(4)  INIT_F(5)  INIT_F(6)  INIT_F(7)
            INIT_F(8)  INIT_F(9)  INIT_F(10) INIT_F(11)
            INIT_F(12) INIT_F(13) INIT_F(14) INIT_F(15)
#undef INIT_F
        } else {
            const float* ra_ = transitions + (size_t)(2 * g) * N + 32 * k;
            const float* rb_ = transitions + (size_t)(2 * g + 1) * N + 32 * k;
#define INIT_B(m)                                                              \
            {                                                                  \
                f2 r0 = *reinterpret_cast<const f2*>(ra_ + 2 * (m));           \
                f2 r1 = *reinterpret_cast<const f2*>(rb_ + 2 * (m));           \
                EA_##m = PKRTZ(__builtin_amdgcn_exp2f(r0.x * LOG2E),           \
                               __builtin_amdgcn_exp2f(r0.y * LOG2E));          \
                EB_##m = PKRTZ(__builtin_amdgcn_exp2f(r1.x * LOG2E),           \
                               __builtin_amdgcn_exp2f(r1.y * LOG2E));          \
            }
            INIT_B(0)  INIT_B(1)  INIT_B(2)  INIT_B(3)
            INIT_B(4)  INIT_B(5)  INIT_B(6)  INIT_B(7)
            INIT_B(8)  INIT_B(9)  INIT_B(10) INIT_B(11)
            INIT_B(12) INIT_B(13) INIT_B(14) INIT_B(15)
#undef INIT_B
        }

        int n_steps, e0, dstep; bool zfinal;
        if (isf) {
            n_steps = qa; e0 = 1; dstep = 1; zfinal = false;
        } else {
            int total = T - qc;
            n_steps = total > 0 ? total - 1 : 0;
            e0 = len - 2; if (e0 < 0) e0 = 0;
            dstep = -1;
            zfinal = total > 0;
        }

        int o = 0, cur = 0;
        float qA, qB;
        {
            const float* base = isf ? start_t : end_t;
            f2 bt = *reinterpret_cast<const f2*>(base + 2 * g);
            f2 ev;
            if (isf)         ev = *reinterpret_cast<const f2*>(eb + 2 * g);
            else if (zfinal) ev = *reinterpret_cast<const f2*>(eb + (size_t)(len - 1) * N + 2 * g);
            else           { ev.x = 0.f; ev.y = 0.f; }
            qA = __builtin_amdgcn_exp2f((bt.x + ev.x) * LOG2E);
            qB = __builtin_amdgcn_exp2f((bt.y + ev.y) * LOG2E);
            if (k == 0)
                pbuf[0][(g >> 4) * 20 + (g & 15)] =
                    __builtin_bit_cast(float, PKRTZ(qA, qB));
        }
        LDS_BARRIER();

        auto eidx = [&](int n) {
            int nn2 = (n < n_steps) ? n : (n_steps - 1);
            if (nn2 < 0) nn2 = 0;
            return e0 + dstep * nn2;
        };
        auto ldE = [&](int tt) {
            return *reinterpret_cast<const f2*>(eb + (size_t)tt * N + 2 * g);
        };

        auto STEP = [&](f2 ecur) {
            float q0w = pbuf[cur][0];
            const float4* pv = reinterpret_cast<const float4*>(&pbuf[cur][k * 20]);
            float4 Qa = pv[0], Qb = pv[1], Qc = pv[2], Qd = pv[3];

            unsigned u0 = __float_as_uint(q0w);
            int eS = (int)((u0 >> 10) & 0x1Fu) - 15;
            o += eS;
            float feS = (float)eS;
            float esA = __builtin_amdgcn_exp2f(ecur.x * LOG2E - feS);
            float esB = __builtin_amdgcn_exp2f(ecur.y * LOG2E - feS);

            float aA0 = 0.f, aA1 = 0.f, aB0 = 0.f, aB1 = 0.f;
#define D0(m_, Qc_)                                                            \
            {                                                                  \
                h2 pm = __builtin_bit_cast(h2, Qc_);                           \
                aA0 = __builtin_amdgcn_fdot2(pm, EA_##m_, aA0, false);         \
                aB0 = __builtin_amdgcn_fdot2(pm, EB_##m_, aB0, false);         \
            }
#define D1(m_, Qc_)                                                            \
            {                                                                  \
                h2 pm = __builtin_bit_cast(h2, Qc_);                           \
                aA1 = __builtin_amdgcn_fdot2(pm, EA_##m_, aA1, false);         \
                aB1 = __builtin_amdgcn_fdot2(pm, EB_##m_, aB1, false);         \
            }
            D0(0,  Qa.x) D1(1,  Qa.y) D0(2,  Qa.z) D1(3,  Qa.w)
            D0(4,  Qb.x) D1(5,  Qb.y) D0(6,  Qb.z) D1(7,  Qb.w)
            D0(8,  Qc.x) D1(9,  Qc.y) D0(10, Qc.z) D1(11, Qc.w)
            D0(12, Qd.x) D1(13, Qd.y) D0(14, Qd.z) D1(15, Qd.w)
#undef D0
#undef D1
            float dA = aA0 + aA1;
            float dB = aB0 + aB1;
            dA += dpp_f<0xB1>(dA); dB += dpp_f<0xB1>(dB);
            dA += dpp_f<0x4E>(dA); dB += dpp_f<0x4E>(dB);

            qA = esA * dA;
            qB = esB * dB;
            cur ^= 1;
            if (k == 0)
                pbuf[cur][(g >> 4) * 20 + (g & 15)] =
                    __builtin_bit_cast(float, PKRTZ(qA, qB));
            LDS_BARRIER();
        };

        f2 ra = ldE(eidx(0));
        f2 rb = ldE(eidx(1));
        f2 rc = ldE(eidx(2));
        f2 rd = ldE(eidx(3));

        int n = 0;
        while (n < n_steps) {
            STEP(ra); ra = ldE(eidx(n + 4)); ++n; if (n >= n_steps) break;
            STEP(rb); rb = ldE(eidx(n + 4)); ++n; if (n >= n_steps) break;
            STEP(rc); rc = ldE(eidx(n + 4)); ++n; if (n >= n_steps) break;
            STEP(rd); rd = ldE(eidx(n + 4)); ++n;
        }
        if (zfinal) { f2 z; z.x = 0.f; z.y = 0.f; STEP(z); }

        float* wv = wsV + (size_t)(role * 64 + b) * 128;
        if (k == 0) {
            f2 q; q.x = qA; q.y = qB;
            *reinterpret_cast<f2*>(wv + 2 * g) = q;
        }
        if (tid == 0) wsO[role * 64 + b] = o;

    } else {
        // ================= MATRIX ROLES: 16x16x32 MFMA ======================
        const int w     = tid >> 6;       // wave = strip cols [32w, 32w+32)
        const int lidx  = tid & 63;
        const int lq    = (tid >> 4) & 3; // lane>>4
        const int m15   = tid & 15;       // lane&15
        const int matid = role - 2;
        const int tlo   = matid ? qb : qa;
        const int nm    = matid ? (qc - qb) : (qb - qa);

        // ---- A = E^T fragments (const): Afr[rt][ks], A[m][k] = exp(T[kg][mg])
        // mg = 16rt + m15, kg = 32ks + mu(lq,e), mu = 4lq + (e&3) + 16*(e>>2)
        h8 Afr[8][4];
        #pragma unroll
        for (int rt = 0; rt < 8; ++rt) {
            #pragma unroll
            for (int ks = 0; ks < 4; ++ks) {
                u4 au;
                #pragma unroll
                for (int ep = 0; ep < 4; ++ep) {
                    int ee0 = 2 * ep, ee1 = 2 * ep + 1;
                    int k0 = 32 * ks + 4 * lq + (ee0 & 3) + 16 * (ee0 >> 2);
                    int k1 = 32 * ks + 4 * lq + (ee1 & 3) + 16 * (ee1 >> 2);
                    float v0 = __builtin_amdgcn_exp2f(
                        transitions[k0 * N + 16 * rt + m15] * LOG2E);
                    float v1 = __builtin_amdgcn_exp2f(
                        transitions[k1 * N + 16 * rt + m15] * LOG2E);
                    au[ep] = BITS(PKRTZ(v0, v1));
                }
                Afr[rt][ks] = __builtin_bit_cast(h8, au);
            }
        }

        // ---- B init = identity strip: B[ks][ct] slot e = 1 iff
        // 32ks + mu(lq,e) == 32w + 16ct + m15
        h8 Bf[4][2];
        #pragma unroll
        for (int ks = 0; ks < 4; ++ks) {
            #pragma unroll
            for (int ct = 0; ct < 2; ++ct) {
                u4 bu; bu[0] = 0u; bu[1] = 0u; bu[2] = 0u; bu[3] = 0u;
                #pragma unroll
                for (int e = 0; e < 8; ++e) {
                    int kk = 32 * ks + 4 * lq + (e & 3) + 16 * (e >> 2);
                    if (kk == 32 * w + 16 * ct + m15)
                        bu[e >> 1] |= 0x3C00u << (16 * (e & 1));
                }
                Bf[ks][ct] = __builtin_bit_cast(h8, bu);
            }
        }
        int o = 0;

        auto ldEm = [&](int q) {
            int qq = q; if (qq > nm - 1) qq = nm - 1; if (qq < 0) qq = 0;
            int t = tlo + 1 + qq;
            return *reinterpret_cast<const f2*>(eb + (size_t)t * N + 2 * lidx);
        };

        auto STEPm = [&](f2 ev) {
            // s broadcast within wave via sbuf (write own pair, read b128 runs)
            f2 sp;
            sp.x = __builtin_amdgcn_exp2f(ev.x * LOG2E);
            sp.y = __builtin_amdgcn_exp2f(ev.y * LOG2E);
            *reinterpret_cast<f2*>(&sbuf[w][2 * lidx]) = sp;
            LGKM0();
            f4 srt[8];
            #pragma unroll
            for (int rt = 0; rt < 8; ++rt)
                srt[rt] = *reinterpret_cast<const f4*>(&sbuf[w][16 * rt + 4 * lq]);

            // 16 independent 4-deep MFMA chains (issue-bound)
            f4 Dr[8][2];
            #pragma unroll
            for (int rt = 0; rt < 8; ++rt) {
                #pragma unroll
                for (int ct = 0; ct < 2; ++ct) {
                    f4 d = {0.f, 0.f, 0.f, 0.f};
                    #pragma unroll
                    for (int ks = 0; ks < 4; ++ks)
                        d = __builtin_amdgcn_mfma_f32_16x16x32_f16(
                            Afr[rt][ks], Bf[ks][ct], d, 0, 0, 0);
                    Dr[rt][ct] = d;
                }
            }

            // renorm from reference element (lane 0: row 0, col 32w)
            int rb_ = __builtin_amdgcn_readfirstlane(__float_as_int(Dr[0][0][0]));
            int ex = (int)(((unsigned)rb_ >> 23) & 255u) - 127;
            if (ex > 24) ex = 24; if (ex < -24) ex = -24;
            o += ex;
            float sc = __int_as_float((unsigned)(127 - ex) << 23);

            f4 ssr[8];
            #pragma unroll
            for (int rt = 0; rt < 8; ++rt) ssr[rt] = srt[rt] * sc;

            // intra-lane repack D -> B (slot e <- D[2ks+(e>>2)][ct] reg e&3)
            #pragma unroll
            for (int ks = 0; ks < 4; ++ks) {
                #pragma unroll
                for (int ct = 0; ct < 2; ++ct) {
                    u4 bu;
                    bu[0] = BITS(PKRTZ(Dr[2*ks][ct][0]   * ssr[2*ks][0],
                                       Dr[2*ks][ct][1]   * ssr[2*ks][1]));
                    bu[1] = BITS(PKRTZ(Dr[2*ks][ct][2]   * ssr[2*ks][2],
                                       Dr[2*ks][ct][3]   * ssr[2*ks][3]));
                    bu[2] = BITS(PKRTZ(Dr[2*ks+1][ct][0] * ssr[2*ks+1][0],
                                       Dr[2*ks+1][ct][1] * ssr[2*ks+1][1]));
                    bu[3] = BITS(PKRTZ(Dr[2*ks+1][ct][2] * ssr[2*ks+1][2],
                                       Dr[2*ks+1][ct][3] * ssr[2*ks+1][3]));
                    Bf[ks][ct] = __builtin_bit_cast(h8, bu);
                }
            }
        };

        f2 ra = ldEm(0), rb = ldEm(1);
        int q = 0;
        while (q + 1 < nm) {
            STEPm(ra); ra = ldEm(q + 2);
            STEPm(rb); rb = ldEm(q + 3);
            q += 2;
        }
        if (q < nm) STEPm(ra);

        // ---- store strip as M_store[c][row] (combine reads M[i][j] with
        // i = alpha-index = strip col c, j = row)
        {
            _Float16* wmb = wsMh + (size_t)(matid * 64 + b) * 128 * 128;
            #pragma unroll
            for (int ct = 0; ct < 2; ++ct) {
                _Float16* wm = wmb + (size_t)(32 * w + 16 * ct + m15) * 128;
                #pragma unroll
                for (int ks = 0; ks < 4; ++ks) {
                    u4 bu = __builtin_bit_cast(u4, Bf[ks][ct]);
                    #pragma unroll
                    for (int e = 0; e < 8; ++e) {
                        int row = 32 * ks + 4 * lq + (e & 3) + 16 * (e >> 2);
                        unsigned dw = bu[e >> 1];
                        unsigned short us = (unsigned short)((e & 1) ? (dw >> 16)
                                                                     : (dw & 0xFFFFu));
                        wm[row] = __builtin_bit_cast(_Float16, us);
                    }
                }
            }
        }
        if (lidx == 0) wsMo[(matid * 64 + b) * 4 + w] = o;
    }
}

__global__ __launch_bounds__(128)
void crf_combine(const float* __restrict__ wsV, const int* __restrict__ wsO,
                 const int* __restrict__ wsMo, const _Float16* __restrict__ wsMh,
                 float* __restrict__ out)
{
    const int b = blockIdx.x;
    const int j = threadIdx.x;   // 0..127
    __shared__ float stage[128];
    __shared__ float redw[2];

    int o10 = wsMo[(0 * 64 + b) * 4 + 0], o11 = wsMo[(0 * 64 + b) * 4 + 1];
    int o12 = wsMo[(0 * 64 + b) * 4 + 2], o13 = wsMo[(0 * 64 + b) * 4 + 3];
    int o20 = wsMo[(1 * 64 + b) * 4 + 0], o21 = wsMo[(1 * 64 + b) * 4 + 1];
    int o22 = wsMo[(1 * 64 + b) * 4 + 2], o23 = wsMo[(1 * 64 + b) * 4 + 3];
    int O1 = max(max(o10, o11), max(o12, o13));
    int O2 = max(max(o20, o21), max(o22, o23));

    float al = wsV[(size_t)(0 * 64 + b) * 128 + j];
    int r1 = wsMo[(0 * 64 + b) * 4 + (j >> 5)];
    stage[j] = al * __builtin_amdgcn_exp2f((float)(r1 - O1));
    __syncthreads();

    float v1 = 0.f;
    const _Float16* M1 = wsMh + (size_t)(0 * 64 + b) * 128 * 128;
    #pragma unroll 8
    for (int i = 0; i < 128; ++i)
        v1 += stage[i] * (float)M1[(size_t)i * 128 + j];
    __syncthreads();

    int r2 = wsMo[(1 * 64 + b) * 4 + (j >> 5)];
    stage[j] = v1 * __builtin_amdgcn_exp2f((float)(r2 - O2));
    __syncthreads();

    float v2 = 0.f;
    const _Float16* M2 = wsMh + (size_t)(1 * 64 + b) * 128 * 128;
    #pragma unroll 8
    for (int i = 0; i < 128; ++i)
        v2 += stage[i] * (float)M2[(size_t)i * 128 + j];

    float term = v2 * wsV[(size_t)(1 * 64 + b) * 128 + j];
    #pragma unroll
    for (int s = 1; s < 64; s <<= 1) term += __shfl_xor(term, s);
    if ((j & 63) == 0) redw[j >> 6] = term;
    __syncthreads();
    if (j == 0) {
        float V = redw[0] + redw[1];
        out[b] = LN2 * ((float)(wsO[b] + wsO[64 + b] + O1 + O2) +
                        __builtin_amdgcn_logf(V));
    }
}

extern "C" void kernel_launch(void* const* d_in, const int* in_sizes, int n_in,
                              void* d_out, int out_size, void* d_ws, size_t ws_size,
                              hipStream_t stream) {
    const float* emissions   = (const float*)d_in[0];
    const float* transitions = (const float*)d_in[1];
    const float* start_t     = (const float*)d_in[2];
    const float* end_t       = (const float*)d_in[3];
    const int*   lengths     = (const int*)d_in[4];
    float* out = (float*)d_out;

    float*    wsV  = (float*)d_ws;                          // 65536 B
    int*      wsO  = (int*)((char*)d_ws + 65536);           // 512 B
    int*      wsMo = (int*)((char*)d_ws + 66048);           // 2048 B
    _Float16* wsMh = (_Float16*)((char*)d_ws + 68096);      // 4 MB

    crf_fused<<<dim3(256), dim3(256), 0, stream>>>(
        emissions, transitions, start_t, end_t, lengths, wsV, wsO, wsMo, wsMh);
    crf_combine<<<dim3(64), dim3(128), 0, stream>>>(wsV, wsO, wsMo, wsMh, out);
}